// Round 6
// baseline (153.639 us; speedup 1.0000x reference)
//
#include <hip/hip_runtime.h>

typedef _Float16 half8 __attribute__((ext_vector_type(8)));
typedef float floatx16 __attribute__((ext_vector_type(16)));

#define TPB   256            // 4 waves; each wave owns ONE 32-query A-frag
#define RPTS  512            // db points staged per round (16 KiB -> 8 blocks/CU)
#define NTILE (RPTS / 32)    // 16 tiles of 32 db points per round
#define SMH   (RPTS * 16)    // 8192 halfs = 16 KiB

// 32x32x16 f16 MFMA, occupancy-first variant: 128 queries/block, 2048 blocks,
// 8 blocks/CU = 32 waves/CU = 8 waves/SIMD. K-slots (11 of 16 used):
//   B: (xh, xl, xh, yh, yl, yh, zh, zl | zh, hqh, hql, 0..)
//   A: (-xh,-xh,-xl,-yh,-yh,-yl,-zh,-zh | -zl, 1, 1, 0..)
// => acc = 0.5||q||^2 - p.q (split-f16, ~5e-5);  dist = 2*(ph + min acc).
// A: row m = lane&31, k = (lane>>5)*8 + j.  B: col = lane&31, same k.
// C/D: col = lane&31, row = (reg&3) + 8*(reg>>2) + 4*(lane>>5).
__global__ __launch_bounds__(TPB, 8) void chamfer_mfma(const float* __restrict__ xyz1,
                                                       const float* __restrict__ xyz2,
                                                       float* __restrict__ out,
                                                       int N, int M) {
    const int b = blockIdx.y, dir = blockIdx.z;
    const float* __restrict__ P = dir ? xyz2 + (size_t)b * M * 3 : xyz1 + (size_t)b * N * 3;
    const float* __restrict__ Q = dir ? xyz1 + (size_t)b * N * 3 : xyz2 + (size_t)b * M * 3;
    const int nq = dir ? M : N;
    const int md = dir ? N : M;

    if ((int)blockIdx.x * 128 >= nq) return;   // block-uniform, before any barrier

    __shared__ __align__(16) _Float16 smB[SMH];

    const int tid = (int)threadIdx.x;
    const int w   = tid >> 6;
    const int l   = tid & 63;
    const int m   = l & 31;      // A row / B col this lane serves
    const int h   = l >> 5;      // k-half: k = h*8 + j

    const _Float16 hz = (_Float16)0.0f, hone = (_Float16)1.0f;
    const int qb = blockIdx.x * 128 + w * 32;   // this wave's query base

    // ---- Build the wave's single A-fragment (held for the whole kernel) ----
    half8 afr;
    {
        int idx = qb + m;
        int ci  = idx < nq ? idx : nq - 1;
        float x = P[3 * ci], y = P[3 * ci + 1], z = P[3 * ci + 2];
        _Float16 xh = (_Float16)x, yh = (_Float16)y, zh = (_Float16)z;
        _Float16 xl = (_Float16)(x - (float)xh);
        _Float16 yl = (_Float16)(y - (float)yh);
        _Float16 zl = (_Float16)(z - (float)zh);
        if (h == 0) {
            afr[0] = -xh; afr[1] = -xh; afr[2] = -xl; afr[3] = -yh;
            afr[4] = -yh; afr[5] = -yl; afr[6] = -zh; afr[7] = -zh;
        } else {
            afr[0] = -zl; afr[1] = hone; afr[2] = hone; afr[3] = hz;
            afr[4] = hz;  afr[5] = hz;   afr[6] = hz;  afr[7] = hz;
        }
    }

    float rm[16];
#pragma unroll
    for (int i = 0; i < 16; ++i) rm[i] = 3.0e38f;

    const floatx16 czero = {0.0f, 0.0f, 0.0f, 0.0f, 0.0f, 0.0f, 0.0f, 0.0f,
                            0.0f, 0.0f, 0.0f, 0.0f, 0.0f, 0.0f, 0.0f, 0.0f};
    const int nrounds = (md + RPTS - 1) / RPTS;
    const _Float16* bp = smB + h * 256 + m * 8;

    for (int r = 0; r < nrounds; ++r) {
        if (r) __syncthreads();   // WAR guard before restaging
        // ---- Stage 512 db points as pre-formatted B-fragments (2 pts/thread) ----
#pragma unroll
        for (int k = 0; k < RPTS / TPB; ++k) {
            int j = tid + k * TPB;
            int g = r * RPTS + j;
            g = g < md ? g : md - 1;              // clamp-pad: dups never change a min
            float x = Q[3 * g], y = Q[3 * g + 1], z = Q[3 * g + 2];
            float hq = 0.5f * (x * x + y * y + z * z);
            _Float16 xh = (_Float16)x, yh = (_Float16)y, zh = (_Float16)z;
            _Float16 xl = (_Float16)(x - (float)xh);
            _Float16 yl = (_Float16)(y - (float)yh);
            _Float16 zl = (_Float16)(z - (float)zh);
            _Float16 qh = (_Float16)hq;
            _Float16 ql = (_Float16)(hq - (float)qh);
            int t = j >> 5, c = j & 31;
            half8 v0, v1;
            v0[0] = xh; v0[1] = xl; v0[2] = xh; v0[3] = yh;
            v0[4] = yl; v0[5] = yh; v0[6] = zh; v0[7] = zl;
            v1[0] = zh; v1[1] = qh; v1[2] = ql; v1[3] = hz;
            v1[4] = hz; v1[5] = hz; v1[6] = hz; v1[7] = hz;
            *(half8*)&smB[t * 512 + c * 8]       = v0;   // k-half 0
            *(half8*)&smB[t * 512 + 256 + c * 8] = v1;   // k-half 1
        }
        __syncthreads();

        // ---- Sweep: 16 tiles, 2 per iteration; min3 fold ----
        for (int t = 0; t < NTILE; t += 2) {
            half8 b0 = *(const half8*)(bp + t * 512);
            half8 b1 = *(const half8*)(bp + t * 512 + 512);
            floatx16 da = __builtin_amdgcn_mfma_f32_32x32x16_f16(afr, b0, czero, 0, 0, 0);
            floatx16 db = __builtin_amdgcn_mfma_f32_32x32x16_f16(afr, b1, czero, 0, 0, 0);
#pragma unroll
            for (int i = 0; i < 16; ++i)
                rm[i] = fminf(fminf(rm[i], da[i]), db[i]);   // -> v_min3
        }
    }

    // ---- Col-min across the 32 lanes of each k-half ----
#pragma unroll
    for (int off = 1; off < 32; off <<= 1) {
#pragma unroll
        for (int i = 0; i < 16; ++i) rm[i] = fminf(rm[i], __shfl_xor(rm[i], off, 64));
    }

    // ---- Emit: lanes m<16 of each half own one row each (reg = m) ----
    float s = 0.0f;
    if (m < 16) {
        const int row = (m & 3) + 8 * (m >> 2) + 4 * h;
        const int idx = qb + row;
        if (idx < nq) {
            // select rm[m] without dynamic indexing (avoid scratch)
            float v = rm[0];
#pragma unroll
            for (int r2 = 1; r2 < 16; ++r2) v = (m == r2) ? rm[r2] : v;
            float x = P[3 * idx], y = P[3 * idx + 1], z = P[3 * idx + 2];
            s = v + 0.5f * (x * x + y * y + z * z);
        }
    }
#pragma unroll
    for (int off = 32; off > 0; off >>= 1) s += __shfl_down(s, off, 64);
    if (l == 0) atomicAdd(out + b, s * (2.0f / (float)nq));   // dist = 2*(ph+acc)
}

extern "C" void kernel_launch(void* const* d_in, const int* in_sizes, int n_in,
                              void* d_out, int out_size, void* d_ws, size_t ws_size,
                              hipStream_t stream) {
    const float* xyz1 = (const float*)d_in[0];
    const float* xyz2 = (const float*)d_in[1];
    float* out = (float*)d_out;

    const int B = out_size;
    const int N = in_sizes[0] / (3 * B);
    const int M = in_sizes[1] / (3 * B);

    hipMemsetAsync(d_out, 0, (size_t)B * sizeof(float), stream);

    const int qmax = N > M ? N : M;
    dim3 grid((qmax + 127) / 128, B, 2);
    chamfer_mfma<<<grid, dim3(TPB), 0, stream>>>(xyz1, xyz2, out, N, M);
}

// Round 7
// 117.921 us; speedup vs baseline: 1.3029x; 1.3029x over previous
//
#include <hip/hip_runtime.h>

typedef _Float16 half8 __attribute__((ext_vector_type(8)));
typedef float floatx16 __attribute__((ext_vector_type(16)));

#define TPB   256            // 4 waves; each wave owns TWO 32-query A-frags
#define RPTS  1024           // db points per round (32 KiB LDS image)
#define NTILE (RPTS / 32)    // 32 tiles of 32 db points per round
#define SMH   (RPTS * 16)    // 16384 halfs = 32 KiB

// ---------- order-preserving float<->uint for atomicMin ----------
__device__ __forceinline__ unsigned enc(float f) {
    int b = __float_as_int(f);
    return (b >= 0) ? ((unsigned)b | 0x80000000u) : ~(unsigned)b;
}
__device__ __forceinline__ float dec(unsigned k) {
    int b = (k & 0x80000000u) ? (int)(k & 0x7FFFFFFFu) : (int)~k;
    return __int_as_float(b);
}

// ---------- pack: pre-build the exact LDS B-fragment image ----------
// Per point (32 halfs): khalf0 = (xh,xl,xh,yh,yl,yh,zh,zl), khalf1 = (zh,hqh,hql,0..)
// Layout per batch: tile t (32 pts): 512 halfs; col c: khalf0 at t*512+c*8, khalf1 +256.
__global__ __launch_bounds__(256) void pack_frags(const float* __restrict__ src,
                                                  _Float16* __restrict__ dst,
                                                  int npts, int npad) {
    const int b = blockIdx.y;
    const int p = blockIdx.x * 256 + (int)threadIdx.x;
    if (p >= npad) return;
    const int g = p < npts ? p : npts - 1;          // clamp-pad: dups never change a min
    const float* sp = src + ((size_t)b * npts + g) * 3;
    float x = sp[0], y = sp[1], z = sp[2];
    float hq = 0.5f * (x * x + y * y + z * z);
    _Float16 xh = (_Float16)x, yh = (_Float16)y, zh = (_Float16)z;
    _Float16 xl = (_Float16)(x - (float)xh);
    _Float16 yl = (_Float16)(y - (float)yh);
    _Float16 zl = (_Float16)(z - (float)zh);
    _Float16 qh = (_Float16)hq;
    _Float16 ql = (_Float16)(hq - (float)qh);
    const _Float16 hz = (_Float16)0.0f;
    half8 v0, v1;
    v0[0] = xh; v0[1] = xl; v0[2] = xh; v0[3] = yh;
    v0[4] = yl; v0[5] = yh; v0[6] = zh; v0[7] = zl;
    v1[0] = zh; v1[1] = qh; v1[2] = ql; v1[3] = hz;
    v1[4] = hz; v1[5] = hz; v1[6] = hz; v1[7] = hz;
    int t = p >> 5, c = p & 31;
    _Float16* base = dst + (size_t)b * npad * 16 + (size_t)t * 512 + c * 8;
    *(half8*)base         = v0;
    *(half8*)(base + 256) = v1;
}

// ---------- main: 32x32x16 f16 MFMA sweep over prepacked frags ----------
// A: (-xh,-xh,-xl,-yh,-yh,-yl,-zh,-zh | -zl, 1, 1, 0..) row m=lane&31, k=(lane>>5)*8+j
// acc = 0.5||q||^2 - p.q ; dist = 2*(ph + min acc).
// C/D: col=lane&31, row=(reg&3)+8*(reg>>2)+4*(lane>>5).
// blockIdx.x = qblk*2 + s; block handles db rounds r = s, s+2, ...
__global__ __launch_bounds__(TPB, 4) void chamfer_ws(const float* __restrict__ xyz1,
                                                     const float* __restrict__ xyz2,
                                                     const _Float16* __restrict__ frag1,
                                                     const _Float16* __restrict__ frag2,
                                                     unsigned* __restrict__ dist,
                                                     int N, int M, int B,
                                                     int p1pad, int p2pad, int qpad) {
    const int b = blockIdx.y, dir = blockIdx.z;
    const float*    __restrict__ P = dir ? xyz2 + (size_t)b * M * 3 : xyz1 + (size_t)b * N * 3;
    const _Float16* __restrict__ F = dir ? frag1 + (size_t)b * p1pad * 16
                                         : frag2 + (size_t)b * p2pad * 16;
    const int nq    = dir ? M : N;
    const int mdpad = dir ? p1pad : p2pad;

    const int qblk = blockIdx.x >> 1;
    const int s    = blockIdx.x & 1;
    if (qblk * 256 >= nq) return;   // block-uniform, before any barrier

    __shared__ __align__(16) _Float16 smB[SMH];

    const int tid = (int)threadIdx.x;
    const int w   = tid >> 6;
    const int l   = tid & 63;
    const int m   = l & 31;      // A row / B col this lane serves
    const int h   = l >> 5;      // k-half: k = h*8 + j

    const _Float16 hz = (_Float16)0.0f, hone = (_Float16)1.0f;
    const int qb = qblk * 256 + w * 64;

    // ---- Build the wave's 2 A-fragments ----
    half8 afr[2];
#pragma unroll
    for (int g = 0; g < 2; ++g) {
        int idx = qb + g * 32 + m;
        int ci  = idx < nq ? idx : nq - 1;
        float x = P[3 * ci], y = P[3 * ci + 1], z = P[3 * ci + 2];
        _Float16 xh = (_Float16)x, yh = (_Float16)y, zh = (_Float16)z;
        _Float16 xl = (_Float16)(x - (float)xh);
        _Float16 yl = (_Float16)(y - (float)yh);
        _Float16 zl = (_Float16)(z - (float)zh);
        half8 a;
        if (h == 0) {
            a[0] = -xh; a[1] = -xh; a[2] = -xl; a[3] = -yh;
            a[4] = -yh; a[5] = -yl; a[6] = -zh; a[7] = -zh;
        } else {
            a[0] = -zl; a[1] = hone; a[2] = hone; a[3] = hz;
            a[4] = hz;  a[5] = hz;   a[6] = hz;  a[7] = hz;
        }
        afr[g] = a;
    }

    float rm[32];
#pragma unroll
    for (int i = 0; i < 32; ++i) rm[i] = 3.0e38f;

    const floatx16 czero = {0.0f, 0.0f, 0.0f, 0.0f, 0.0f, 0.0f, 0.0f, 0.0f,
                            0.0f, 0.0f, 0.0f, 0.0f, 0.0f, 0.0f, 0.0f, 0.0f};
    const int nrounds = mdpad / RPTS;
    const _Float16* bp = smB + h * 256 + m * 8;

    for (int r = s; r < nrounds; r += 2) {
        if (r != s) __syncthreads();   // WAR guard before restaging
        // ---- Stage this round's 32 KiB prepacked image: pure int4 copy ----
        const int4* __restrict__ gsrc = (const int4*)(F + (size_t)r * SMH);
        int4* __restrict__ ldst = (int4*)smB;
#pragma unroll
        for (int k = 0; k < (SMH * 2 / 16) / TPB; ++k) {   // 8 chunks/thread
            int c = k * TPB + tid;
            ldst[c] = gsrc[c];
        }
        __syncthreads();

        // ---- Sweep: 32 tiles, 2 per iteration; min3 fold ----
        for (int t = 0; t < NTILE; t += 2) {
            half8 b0 = *(const half8*)(bp + t * 512);
            half8 b1 = *(const half8*)(bp + t * 512 + 512);
            floatx16 d0a = __builtin_amdgcn_mfma_f32_32x32x16_f16(afr[0], b0, czero, 0, 0, 0);
            floatx16 d0b = __builtin_amdgcn_mfma_f32_32x32x16_f16(afr[0], b1, czero, 0, 0, 0);
#pragma unroll
            for (int i = 0; i < 16; ++i)
                rm[i] = fminf(fminf(rm[i], d0a[i]), d0b[i]);         // -> v_min3
            floatx16 d1a = __builtin_amdgcn_mfma_f32_32x32x16_f16(afr[1], b0, czero, 0, 0, 0);
            floatx16 d1b = __builtin_amdgcn_mfma_f32_32x32x16_f16(afr[1], b1, czero, 0, 0, 0);
#pragma unroll
            for (int i = 0; i < 16; ++i)
                rm[16 + i] = fminf(fminf(rm[16 + i], d1a[i]), d1b[i]);
        }
    }

    // ---- Col-min across the 32 lanes of each k-half ----
#pragma unroll
    for (int off = 1; off < 32; off <<= 1) {
#pragma unroll
        for (int i = 0; i < 32; ++i) rm[i] = fminf(rm[i], __shfl_xor(rm[i], off, 64));
    }

    // ---- Emit partial mins: lanes m<16 of each half own one row each ----
    unsigned* dptr = dist + (size_t)(dir * B + b) * qpad;
    if (m < 16) {
        const int reg = (m & 3) + 4 * (m >> 2);
        const int row = 4 * h + (m & 3) + 8 * (m >> 2);
#pragma unroll
        for (int g = 0; g < 2; ++g) {
            int idx = qb + g * 32 + row;
            if (idx < nq) {
                float x = P[3 * idx], y = P[3 * idx + 1], z = P[3 * idx + 2];
                float v = rm[g * 16 + reg] + 0.5f * (x * x + y * y + z * z);
                atomicMin(dptr + idx, enc(v));
            }
        }
    }
}

// ---------- reduce: decode dist arrays, mean both directions, write out ----------
__global__ __launch_bounds__(256) void reduce_out(const unsigned* __restrict__ dist,
                                                  float* __restrict__ out,
                                                  int N, int M, int B, int qpad) {
    const int b = blockIdx.x;
    const int tid = (int)threadIdx.x;
    float s = 0.0f;
    const unsigned* d0 = dist + (size_t)b * qpad;             // dir 0: nq = N
    const unsigned* d1 = dist + (size_t)(B + b) * qpad;       // dir 1: nq = M
    for (int i = tid; i < N; i += 256) s += dec(d0[i]) * (1.0f / (float)N);
    for (int i = tid; i < M; i += 256) s += dec(d1[i]) * (1.0f / (float)M);
#pragma unroll
    for (int off = 32; off > 0; off >>= 1) s += __shfl_down(s, off, 64);
    __shared__ float red[4];
    if ((tid & 63) == 0) red[tid >> 6] = s;
    __syncthreads();
    if (tid == 0) out[b] = 2.0f * (red[0] + red[1] + red[2] + red[3]);
}

// ---------- fallback (ws too small): proven R5 kernel ----------
__global__ __launch_bounds__(TPB, 4) void chamfer_plain(const float* __restrict__ xyz1,
                                                        const float* __restrict__ xyz2,
                                                        float* __restrict__ out,
                                                        int N, int M) {
    const int b = blockIdx.y, dir = blockIdx.z;
    const float* __restrict__ P = dir ? xyz2 + (size_t)b * M * 3 : xyz1 + (size_t)b * N * 3;
    const float* __restrict__ Q = dir ? xyz1 + (size_t)b * N * 3 : xyz2 + (size_t)b * M * 3;
    const int nq = dir ? M : N;
    const int md = dir ? N : M;
    if ((int)blockIdx.x * TPB >= nq) return;
    __shared__ __align__(16) _Float16 smB[SMH];
    const int tid = (int)threadIdx.x;
    const int w = tid >> 6, l = tid & 63, m = l & 31, h = l >> 5;
    const _Float16 hz = (_Float16)0.0f, hone = (_Float16)1.0f;
    const int qb = blockIdx.x * 256 + w * 64;
    half8 afr[2];
#pragma unroll
    for (int g = 0; g < 2; ++g) {
        int idx = qb + g * 32 + m;
        int ci  = idx < nq ? idx : nq - 1;
        float x = P[3 * ci], y = P[3 * ci + 1], z = P[3 * ci + 2];
        _Float16 xh = (_Float16)x, yh = (_Float16)y, zh = (_Float16)z;
        _Float16 xl = (_Float16)(x - (float)xh);
        _Float16 yl = (_Float16)(y - (float)yh);
        _Float16 zl = (_Float16)(z - (float)zh);
        half8 a;
        if (h == 0) { a[0]=-xh;a[1]=-xh;a[2]=-xl;a[3]=-yh;a[4]=-yh;a[5]=-yl;a[6]=-zh;a[7]=-zh; }
        else        { a[0]=-zl;a[1]=hone;a[2]=hone;a[3]=hz;a[4]=hz;a[5]=hz;a[6]=hz;a[7]=hz; }
        afr[g] = a;
    }
    float rm[32];
#pragma unroll
    for (int i = 0; i < 32; ++i) rm[i] = 3.0e38f;
    const floatx16 czero = {0,0,0,0,0,0,0,0,0,0,0,0,0,0,0,0};
    const int nrounds = (md + RPTS - 1) / RPTS;
    const _Float16* bp = smB + h * 256 + m * 8;
    for (int r = 0; r < nrounds; ++r) {
        if (r) __syncthreads();
#pragma unroll
        for (int k = 0; k < RPTS / TPB; ++k) {
            int j = tid + k * TPB;
            int g = r * RPTS + j;
            g = g < md ? g : md - 1;
            float x = Q[3 * g], y = Q[3 * g + 1], z = Q[3 * g + 2];
            float hq = 0.5f * (x * x + y * y + z * z);
            _Float16 xh = (_Float16)x, yh = (_Float16)y, zh = (_Float16)z;
            _Float16 xl = (_Float16)(x - (float)xh);
            _Float16 yl = (_Float16)(y - (float)yh);
            _Float16 zl = (_Float16)(z - (float)zh);
            _Float16 qh = (_Float16)hq;
            _Float16 ql = (_Float16)(hq - (float)qh);
            int t = j >> 5, c = j & 31;
            half8 v0, v1;
            v0[0]=xh;v0[1]=xl;v0[2]=xh;v0[3]=yh;v0[4]=yl;v0[5]=yh;v0[6]=zh;v0[7]=zl;
            v1[0]=zh;v1[1]=qh;v1[2]=ql;v1[3]=hz;v1[4]=hz;v1[5]=hz;v1[6]=hz;v1[7]=hz;
            *(half8*)&smB[t * 512 + c * 8]       = v0;
            *(half8*)&smB[t * 512 + 256 + c * 8] = v1;
        }
        __syncthreads();
        for (int t = 0; t < NTILE; t += 2) {
            half8 b0 = *(const half8*)(bp + t * 512);
            half8 b1 = *(const half8*)(bp + t * 512 + 512);
            floatx16 d0a = __builtin_amdgcn_mfma_f32_32x32x16_f16(afr[0], b0, czero, 0, 0, 0);
            floatx16 d0b = __builtin_amdgcn_mfma_f32_32x32x16_f16(afr[0], b1, czero, 0, 0, 0);
#pragma unroll
            for (int i = 0; i < 16; ++i) rm[i] = fminf(fminf(rm[i], d0a[i]), d0b[i]);
            floatx16 d1a = __builtin_amdgcn_mfma_f32_32x32x16_f16(afr[1], b0, czero, 0, 0, 0);
            floatx16 d1b = __builtin_amdgcn_mfma_f32_32x32x16_f16(afr[1], b1, czero, 0, 0, 0);
#pragma unroll
            for (int i = 0; i < 16; ++i) rm[16+i] = fminf(fminf(rm[16+i], d1a[i]), d1b[i]);
        }
    }
#pragma unroll
    for (int off = 1; off < 32; off <<= 1) {
#pragma unroll
        for (int i = 0; i < 32; ++i) rm[i] = fminf(rm[i], __shfl_xor(rm[i], off, 64));
    }
    float s = 0.0f;
    if (m < 16) {
        const int reg = (m & 3) + 4 * (m >> 2);
        const int row = 4 * h + (m & 3) + 8 * (m >> 2);
#pragma unroll
        for (int g = 0; g < 2; ++g) {
            int idx = qb + g * 32 + row;
            if (idx < nq) {
                float x = P[3 * idx], y = P[3 * idx + 1], z = P[3 * idx + 2];
                s += rm[g * 16 + reg] + 0.5f * (x * x + y * y + z * z);
            }
        }
    }
#pragma unroll
    for (int off = 32; off > 0; off >>= 1) s += __shfl_down(s, off, 64);
    if (l == 0) atomicAdd(out + b, s * (2.0f / (float)nq));
}

extern "C" void kernel_launch(void* const* d_in, const int* in_sizes, int n_in,
                              void* d_out, int out_size, void* d_ws, size_t ws_size,
                              hipStream_t stream) {
    const float* xyz1 = (const float*)d_in[0];
    const float* xyz2 = (const float*)d_in[1];
    float* out = (float*)d_out;

    const int B = out_size;
    const int N = in_sizes[0] / (3 * B);
    const int M = in_sizes[1] / (3 * B);
    const int qmax = N > M ? N : M;

    const int p1pad = ((N + RPTS - 1) / RPTS) * RPTS;
    const int p2pad = ((M + RPTS - 1) / RPTS) * RPTS;
    const int qpad  = p1pad > p2pad ? p1pad : p2pad;
    const size_t f1bytes = (size_t)B * p1pad * 32;   // 16 halfs *2B per point image? (32 B/pt)
    const size_t f2bytes = (size_t)B * p2pad * 32;
    const size_t dbytes  = (size_t)2 * B * qpad * sizeof(unsigned);

    if (ws_size >= f1bytes + f2bytes + dbytes) {
        _Float16* frag1 = (_Float16*)d_ws;
        _Float16* frag2 = (_Float16*)((char*)d_ws + f1bytes);
        unsigned* dist  = (unsigned*)((char*)d_ws + f1bytes + f2bytes);

        pack_frags<<<dim3(p1pad / 256, B), dim3(256), 0, stream>>>(xyz1, frag1, N, p1pad);
        pack_frags<<<dim3(p2pad / 256, B), dim3(256), 0, stream>>>(xyz2, frag2, M, p2pad);
        hipMemsetAsync(dist, 0xFF, dbytes, stream);

        dim3 grid(((qmax + 255) / 256) * 2, B, 2);   // qblk*2 + db-split bit
        chamfer_ws<<<grid, dim3(TPB), 0, stream>>>(xyz1, xyz2, frag1, frag2, dist,
                                                   N, M, B, p1pad, p2pad, qpad);
        reduce_out<<<dim3(B), dim3(256), 0, stream>>>(dist, out, N, M, B, qpad);
    } else {
        hipMemsetAsync(out, 0, (size_t)B * sizeof(float), stream);
        dim3 grid((qmax + 255) / 256, B, 2);
        chamfer_plain<<<grid, dim3(TPB), 0, stream>>>(xyz1, xyz2, out, N, M);
    }
}